// Round 9
// baseline (880.243 us; speedup 1.0000x reference)
//
#include <hip/hip_runtime.h>
#include <hip/hip_bf16.h>
#include <stdint.h>

#define NE 8
#define DD 2048
#define FF 4096
#define TT 4096      // tokens = 2*2048

typedef __attribute__((ext_vector_type(8))) short bf16x8;
typedef __attribute__((ext_vector_type(4))) float f32x4;

__device__ inline unsigned short f2bf(float f) {
  union { float f; unsigned u; } x; x.f = f;
  unsigned r = x.u + 0x7fffu + ((x.u >> 16) & 1u);
  return (unsigned short)(r >> 16);
}
__device__ inline float bf2f(unsigned short v) {
  union { unsigned u; float f; } x; x.u = (unsigned)v << 16; return x.f;
}
// RNE pack of 2 fp32 -> 2 bf16 in one u32 (lo -> bits[15:0])
__device__ inline unsigned cvtpk(float lo, float hi) {
  unsigned r;
  asm("v_cvt_pk_bf16_f32 %0, %1, %2" : "=v"(r) : "v"(lo), "v"(hi));
  return r;
}
__device__ inline uint4 pk8(float4 a, float4 b) {
  uint4 o;
  o.x = cvtpk(a.x, a.y); o.y = cvtpk(a.z, a.w);
  o.z = cvtpk(b.x, b.y); o.w = cvtpk(b.z, b.w);
  return o;
}

#define GLL16(g, l) __builtin_amdgcn_global_load_lds( \
    (__attribute__((address_space(1))) void*)(void*)(g), \
    (__attribute__((address_space(3))) void*)(l), 16, 0, 0)
#define LDV(p) (*(const bf16x8*)(p))
#define MF(d, a, b) d = __builtin_amdgcn_mfma_f32_16x16x32_bf16(a, b, d, 0, 0, 0)
#define WAITVN(n) asm volatile("s_waitcnt vmcnt(" #n ")" ::: "memory")
#define WAITL0() asm volatile("s_waitcnt lgkmcnt(0)" ::: "memory")
#define SCB() __builtin_amdgcn_sched_barrier(0)

// ---------------- router body (one wave = one token) ----------------
__device__ __forceinline__ void router_one(
    int t, int lane, const float* __restrict__ h, const float* __restrict__ gw,
    float* __restrict__ logits, unsigned short* __restrict__ hb,
    int* __restrict__ counts, int* __restrict__ tok_idx,
    int* __restrict__ sel_e, int* __restrict__ sel_slot, float* __restrict__ sel_w) {
  const float4* hr = (const float4*)(h + (size_t)t * DD);
  float4 hv[8];
  float acc[NE];
#pragma unroll
  for (int e = 0; e < NE; e++) acc[e] = 0.f;
#pragma unroll
  for (int j = 0; j < 8; j++) hv[j] = hr[j * 64 + lane];
  ushort4* hbr = (ushort4*)(hb + (size_t)t * DD);
#pragma unroll
  for (int j = 0; j < 8; j++) {
    ushort4 o;
    o.x = f2bf(hv[j].x); o.y = f2bf(hv[j].y); o.z = f2bf(hv[j].z); o.w = f2bf(hv[j].w);
    hbr[j * 64 + lane] = o;
  }
#pragma unroll
  for (int e = 0; e < NE; e++) {
    const float4* g = (const float4*)(gw + (size_t)e * DD);
    float a = 0.f;
#pragma unroll
    for (int j = 0; j < 8; j++) {
      float4 gv = g[j * 64 + lane];
      a += hv[j].x * gv.x + hv[j].y * gv.y + hv[j].z * gv.z + hv[j].w * gv.w;
    }
    acc[e] = a;
  }
#pragma unroll
  for (int e = 0; e < NE; e++) {
    float v = acc[e];
#pragma unroll
    for (int o = 32; o > 0; o >>= 1) v += __shfl_xor(v, o, 64);
    acc[e] = v;
  }
  if (lane == 0) {
#pragma unroll
    for (int e = 0; e < NE; e++) logits[(size_t)t * NE + e] = acc[e];
    int e1 = 0; float m1 = acc[0];
#pragma unroll
    for (int e = 1; e < NE; e++) if (acc[e] > m1) { m1 = acc[e]; e1 = e; }
    int e2 = -1; float m2 = -3.4e38f;
#pragma unroll
    for (int e = 0; e < NE; e++) if (e != e1 && acc[e] > m2) { m2 = acc[e]; e2 = e; }
    float s = expf(m2 - m1);
    float wa = 1.f / (1.f + s);
    float wb = s * wa;
    int s1 = atomicAdd(&counts[e1], 1);
    tok_idx[e1 * TT + s1] = t;
    int s2 = atomicAdd(&counts[e2], 1);
    tok_idx[e2 * TT + s2] = t;
    sel_e[2 * t] = e1; sel_slot[2 * t] = s1; sel_w[2 * t] = wa;
    sel_e[2 * t + 1] = e2; sel_slot[2 * t + 1] = s2; sel_w[2 * t + 1] = wb;
  }
}

__global__ __launch_bounds__(256) void router_kernel(
    const float* __restrict__ h, const float* __restrict__ gw,
    float* __restrict__ logits, unsigned short* __restrict__ hb,
    int* __restrict__ counts, int* __restrict__ tok_idx,
    int* __restrict__ sel_e, int* __restrict__ sel_slot, float* __restrict__ sel_w) {
  router_one(blockIdx.x * 4 + (threadIdx.x >> 6), threadIdx.x & 63,
             h, gw, logits, hb, counts, tok_idx, sel_e, sel_slot, sel_w);
}

__global__ void offsets_kernel(const int* __restrict__ counts, int* __restrict__ offsets) {
  if (threadIdx.x == 0) {
    int r = 0;
    for (int e = 0; e < NE; e++) { offsets[e] = r; r += counts[e]; }
  }
}

// =========================================================================
// fp32-direct GEMMs. BM=256, BN=128, BK=64, 8 waves (2M x 4N).
// A (bf16) via global_load_lds, double-buffered. B (fp32) reg-staged:
// 4x float4 -> v_cvt_pk_bf16_f32 -> 2x ds_write_b128 into swizzled LDS,
// single-buffered (write/read between the same barrier pair).
// FIFO (gemm1): [B1x4, B3x4, Ax4] -> entry vmcnt(4) drains B; after B
// reissue, vmcnt(8) drains A. Groups pinned with sched_barrier(0).
// =========================================================================

// ---- gemm1_d: gated = silu(X w1^T) * (X w3^T), dual-B, K=DD ----
// grid: 4096 = x(8) * m(16) * q(32); p = x+8q -> n = p&31, e = p>>5
__global__ __launch_bounds__(512, 2) void gemm1_d(
    const float* __restrict__ w1f, const float* __restrict__ w3f,
    const unsigned short* __restrict__ hb, const int* __restrict__ tok_idx,
    const int* __restrict__ counts, const int* __restrict__ offsets,
    unsigned short* __restrict__ gated) {
  __shared__ __align__(16) char lds[98304];  // A[2][32K] @0, B1 @65536, B3 @81920

  int bid = blockIdx.x;
  int x = bid & 7, rest = bid >> 3;
  int m = rest & 15, q = rest >> 4;
  int p = x + 8 * q;
  int n = p & 31, e = p >> 5;
  int cnt = counts[e];
  int row0 = m * 256;
  if (row0 >= cnt) return;
  int offe = offsets[e];
  int tid = threadIdx.x;
  int lane = tid & 63;
  int wv = tid >> 6;
  int wm = wv >> 2, wn = wv & 3;

  int swz = ((tid & 7) ^ ((tid >> 3) & 7)) * 8;   // A source pre-swizzle (8-elem segs)
  int asrc[4];
#pragma unroll
  for (int i = 0; i < 4; i++) {
    int r = i * 64 + (tid >> 3);
    int rr = row0 + r; if (rr >= cnt) rr = cnt - 1;
    asrc[i] = tok_idx[e * TT + rr] * DD + swz;
  }
  int fbase = n * 128;
  const float* w1e = w1f + (long)e * FF * DD;
  const float* w3e = w3f + (long)e * FF * DD;
  int brs = tid >> 2;                  // staging row 0..127
  int bgo = (fbase + brs) * DD + (tid & 3) * 16;
  int s0 = (tid & 3) * 2, p7 = brs & 7;
  int bw0 = brs * 128 + ((s0 ^ p7) * 16);
  int bw1 = brs * 128 + (((s0 + 1) ^ p7) * 16);

  int arow[8], brow[2];
#pragma unroll
  for (int i = 0; i < 8; i++) arow[i] = (wm * 128 + i * 16 + (lane & 15)) * 128;
#pragma unroll
  for (int j = 0; j < 2; j++) brow[j] = (wn * 32 + j * 16 + (lane & 15)) * 128;
  int kx0 = ((lane >> 4) ^ (lane & 7)) * 16;
  int kx1 = ((4 + (lane >> 4)) ^ (lane & 7)) * 16;

  f32x4 acc1[8][2], acc3[8][2];
#pragma unroll
  for (int i = 0; i < 8; i++)
#pragma unroll
    for (int j = 0; j < 2; j++) { acc1[i][j] = (f32x4){0,0,0,0}; acc3[i][j] = (f32x4){0,0,0,0}; }

  // prologue, FIFO order: B1(0)x4, B3(0)x4, A(0)x4
  float4 b1r[4], b3r[4];
#pragma unroll
  for (int i = 0; i < 4; i++) b1r[i] = *(const float4*)(w1e + bgo + i * 4);
#pragma unroll
  for (int i = 0; i < 4; i++) b3r[i] = *(const float4*)(w3e + bgo + i * 4);
  SCB();
  GLL16(hb + asrc[0], lds + tid * 16);
  GLL16(hb + asrc[1], lds + 8192 + tid * 16);
  GLL16(hb + asrc[2], lds + 16384 + tid * 16);
  GLL16(hb + asrc[3], lds + 24576 + tid * 16);
  SCB();

  int cur = 0;
  for (int kt = 0; kt < DD / 64; kt++) {
    bool st = kt < DD / 64 - 1;
    int ko = (kt + 1) * 64;
    int nc = cur ^ 1;

    WAITVN(4);                         // B regs for tile kt ready (A may be in flight)
    SCB();
    *(uint4*)(lds + 65536 + bw0) = pk8(b1r[0], b1r[1]);
    *(uint4*)(lds + 65536 + bw1) = pk8(b1r[2], b1r[3]);
    *(uint4*)(lds + 81920 + bw0) = pk8(b3r[0], b3r[1]);
    *(uint4*)(lds + 81920 + bw1) = pk8(b3r[2], b3r[3]);
    if (st) {                          // issue next-tile B early (hides under MFMA)
#pragma unroll
      for (int i = 0; i < 4; i++) b1r[i] = *(const float4*)(w1e + bgo + ko + i * 4);
#pragma unroll
      for (int i = 0; i < 4; i++) b3r[i] = *(const float4*)(w3e + bgo + ko + i * 4);
    }
    SCB();
    if (st) { WAITVN(8); } else { WAITVN(0); }   // A(kt) in LDS (B(kt+1) stays in flight)
    WAITL0();                                     // ds_writes done
    SCB();
    __builtin_amdgcn_s_barrier();
    SCB();
    if (st) {
      GLL16(hb + asrc[0] + ko, lds + nc * 32768 + tid * 16);
      GLL16(hb + asrc[1] + ko, lds + nc * 32768 + 8192 + tid * 16);
      GLL16(hb + asrc[2] + ko, lds + nc * 32768 + 16384 + tid * 16);
      GLL16(hb + asrc[3] + ko, lds + nc * 32768 + 24576 + tid * 16);
    }
    SCB();
    const char* Ac = lds + cur * 32768;
    bf16x8 b10 = LDV(lds + 65536 + brow[0] + kx0), b11 = LDV(lds + 65536 + brow[1] + kx0);
    bf16x8 b30 = LDV(lds + 81920 + brow[0] + kx0), b31 = LDV(lds + 81920 + brow[1] + kx0);
    bf16x8 c10 = LDV(lds + 65536 + brow[0] + kx1), c11 = LDV(lds + 65536 + brow[1] + kx1);
    bf16x8 c30 = LDV(lds + 81920 + brow[0] + kx1), c31 = LDV(lds + 81920 + brow[1] + kx1);
    __builtin_amdgcn_s_setprio(1);
#pragma unroll
    for (int i = 0; i < 8; i++) {
      bf16x8 a0 = LDV(Ac + arow[i] + kx0);
      MF(acc1[i][0], a0, b10); MF(acc1[i][1], a0, b11);
      MF(acc3[i][0], a0, b30); MF(acc3[i][1], a0, b31);
      bf16x8 a1 = LDV(Ac + arow[i] + kx1);
      MF(acc1[i][0], a1, c10); MF(acc1[i][1], a1, c11);
      MF(acc3[i][0], a1, c30); MF(acc3[i][1], a1, c31);
    }
    __builtin_amdgcn_s_setprio(0);
    SCB();
    __builtin_amdgcn_s_barrier();      // all reads of B (and A cur) done before next writes
    SCB();
    cur = nc;
  }

  // epilogue: silu(c1)*c3 -> bf16
  int r0 = wm * 128 + ((lane >> 4) << 2);
  int c0 = fbase + wn * 32 + (lane & 15);
#pragma unroll
  for (int i = 0; i < 8; i++)
#pragma unroll
    for (int j = 0; j < 2; j++)
#pragma unroll
      for (int r = 0; r < 4; r++) {
        int tr = r0 + i * 16 + r;
        if (row0 + tr < cnt) {
          float g = acc1[i][j][r];
          float sg = g / (1.f + __expf(-g));
          gated[(size_t)(offe + row0 + tr) * FF + (c0 + j * 16)] = f2bf(sg * acc3[i][j][r]);
        }
      }
}

// ---- gemm2_d: eout(bf16) = gated w2^T, single-B, K=FF ----
// grid: 2048 = x(8) * m(16) * q(16); p = x+8q -> n = p&15, e = p>>4
// FIFO: [Bx4, Ax4] -> entry vmcnt(4) drains B; after reissue vmcnt(4) drains A.
__global__ __launch_bounds__(512, 2) void gemm2_d(
    const float* __restrict__ w2f, const unsigned short* __restrict__ gated,
    const int* __restrict__ counts, const int* __restrict__ offsets,
    unsigned short* __restrict__ eout) {
  __shared__ __align__(16) char lds[81920];  // A[2][32K] @0, B @65536

  int bid = blockIdx.x;
  int x = bid & 7, rest = bid >> 3;
  int m = rest & 15, q = rest >> 4;
  int p = x + 8 * q;
  int n = p & 15, e = p >> 4;
  int cnt = counts[e];
  int row0 = m * 256;
  if (row0 >= cnt) return;
  int offe = offsets[e];
  int tid = threadIdx.x;
  int lane = tid & 63;
  int wv = tid >> 6;
  int wm = wv >> 2, wn = wv & 3;

  int swz = ((tid & 7) ^ ((tid >> 3) & 7)) * 8;
  int asrc[4];
#pragma unroll
  for (int i = 0; i < 4; i++) {
    int r = i * 64 + (tid >> 3);
    int rr = row0 + r; if (rr >= cnt) rr = cnt - 1;
    asrc[i] = (offe + rr) * FF + swz;
  }
  int dbase = n * 128;
  const float* w2e = w2f + (long)e * DD * FF;
  int brs = tid >> 2;
  int bgo = (dbase + brs) * FF + (tid & 3) * 16;
  int s0 = (tid & 3) * 2, p7 = brs & 7;
  int bw0 = brs * 128 + ((s0 ^ p7) * 16);
  int bw1 = brs * 128 + (((s0 + 1) ^ p7) * 16);

  int arow[8], brow[2];
#pragma unroll
  for (int i = 0; i < 8; i++) arow[i] = (wm * 128 + i * 16 + (lane & 15)) * 128;
#pragma unroll
  for (int j = 0; j < 2; j++) brow[j] = (wn * 32 + j * 16 + (lane & 15)) * 128;
  int kx0 = ((lane >> 4) ^ (lane & 7)) * 16;
  int kx1 = ((4 + (lane >> 4)) ^ (lane & 7)) * 16;

  f32x4 acc[8][2];
#pragma unroll
  for (int i = 0; i < 8; i++)
#pragma unroll
    for (int j = 0; j < 2; j++) acc[i][j] = (f32x4){0,0,0,0};

  // prologue, FIFO order: B(0)x4, A(0)x4
  float4 br[4];
#pragma unroll
  for (int i = 0; i < 4; i++) br[i] = *(const float4*)(w2e + bgo + i * 4);
  SCB();
  GLL16(gated + asrc[0], lds + tid * 16);
  GLL16(gated + asrc[1], lds + 8192 + tid * 16);
  GLL16(gated + asrc[2], lds + 16384 + tid * 16);
  GLL16(gated + asrc[3], lds + 24576 + tid * 16);
  SCB();

  int cur = 0;
  for (int kt = 0; kt < FF / 64; kt++) {
    bool st = kt < FF / 64 - 1;
    int ko = (kt + 1) * 64;
    int nc = cur ^ 1;

    WAITVN(4);
    SCB();
    *(uint4*)(lds + 65536 + bw0) = pk8(br[0], br[1]);
    *(uint4*)(lds + 65536 + bw1) = pk8(br[2], br[3]);
    if (st) {
#pragma unroll
      for (int i = 0; i < 4; i++) br[i] = *(const float4*)(w2e + bgo + ko + i * 4);
    }
    SCB();
    if (st) { WAITVN(4); } else { WAITVN(0); }
    WAITL0();
    SCB();
    __builtin_amdgcn_s_barrier();
    SCB();
    if (st) {
      GLL16(gated + asrc[0] + ko, lds + nc * 32768 + tid * 16);
      GLL16(gated + asrc[1] + ko, lds + nc * 32768 + 8192 + tid * 16);
      GLL16(gated + asrc[2] + ko, lds + nc * 32768 + 16384 + tid * 16);
      GLL16(gated + asrc[3] + ko, lds + nc * 32768 + 24576 + tid * 16);
    }
    SCB();
    const char* Ac = lds + cur * 32768;
    bf16x8 b0 = LDV(lds + 65536 + brow[0] + kx0), b1 = LDV(lds + 65536 + brow[1] + kx0);
    bf16x8 b2 = LDV(lds + 65536 + brow[0] + kx1), b3 = LDV(lds + 65536 + brow[1] + kx1);
    __builtin_amdgcn_s_setprio(1);
#pragma unroll
    for (int i = 0; i < 8; i++) {
      bf16x8 a0 = LDV(Ac + arow[i] + kx0);
      MF(acc[i][0], a0, b0); MF(acc[i][1], a0, b1);
      bf16x8 a1 = LDV(Ac + arow[i] + kx1);
      MF(acc[i][0], a1, b2); MF(acc[i][1], a1, b3);
    }
    __builtin_amdgcn_s_setprio(0);
    SCB();
    __builtin_amdgcn_s_barrier();
    SCB();
    cur = nc;
  }

  int r0 = wm * 128 + ((lane >> 4) << 2);
  int c0 = dbase + wn * 32 + (lane & 15);
#pragma unroll
  for (int i = 0; i < 8; i++)
#pragma unroll
    for (int j = 0; j < 2; j++)
#pragma unroll
      for (int r = 0; r < 4; r++) {
        int tr = r0 + i * 16 + r;
        if (row0 + tr < cnt)
          eout[(size_t)(offe + row0 + tr) * DD + (c0 + j * 16)] = f2bf(acc[i][j][r]);
      }
}

// ---------------- gather: final = sum_k w_k * eout[slot_k] (bf16 eout) ----------------
__global__ void gather_kernel(const unsigned short* __restrict__ eout, const int* __restrict__ offsets,
                              const int* __restrict__ sel_e, const int* __restrict__ sel_slot,
                              const float* __restrict__ sel_w, float* __restrict__ out) {
  int idx = blockIdx.x * 256 + threadIdx.x;
  int t = idx >> 8;            // 256 chunks of 8 per row
  int c = (idx & 255) * 8;
  int ea = sel_e[2 * t], eb = sel_e[2 * t + 1];
  long sa = (long)(offsets[ea] + sel_slot[2 * t]) * DD + c;
  long sb = (long)(offsets[eb] + sel_slot[2 * t + 1]) * DD + c;
  float wa = sel_w[2 * t], wb = sel_w[2 * t + 1];
  union { uint4 v; unsigned short h[8]; } va, vb;
  va.v = *(const uint4*)(eout + sa);
  vb.v = *(const uint4*)(eout + sb);
  float4 o0, o1;
  o0.x = wa * bf2f(va.h[0]) + wb * bf2f(vb.h[0]);
  o0.y = wa * bf2f(va.h[1]) + wb * bf2f(vb.h[1]);
  o0.z = wa * bf2f(va.h[2]) + wb * bf2f(vb.h[2]);
  o0.w = wa * bf2f(va.h[3]) + wb * bf2f(vb.h[3]);
  o1.x = wa * bf2f(va.h[4]) + wb * bf2f(vb.h[4]);
  o1.y = wa * bf2f(va.h[5]) + wb * bf2f(vb.h[5]);
  o1.z = wa * bf2f(va.h[6]) + wb * bf2f(vb.h[6]);
  o1.w = wa * bf2f(va.h[7]) + wb * bf2f(vb.h[7]);
  float* op = out + (size_t)t * DD + c;
  *(float4*)op = o0;
  *(float4*)(op + 4) = o1;
}

extern "C" void kernel_launch(void* const* d_in, const int* in_sizes, int n_in,
                              void* d_out, int out_size, void* d_ws, size_t ws_size,
                              hipStream_t stream) {
  const float* h  = (const float*)d_in[0];
  const float* gw = (const float*)d_in[1];
  const float* w1 = (const float*)d_in[2];
  const float* w2 = (const float*)d_in[3];
  const float* w3 = (const float*)d_in[4];
  float* out = (float*)d_out;
  float* logits = out + (size_t)TT * DD;

  char* wp = (char*)d_ws;
  int* counts = (int*)wp; wp += 256;
  int* offsets = (int*)wp; wp += 256;
  int* tok_idx = (int*)wp; wp += (size_t)NE * TT * 4;
  int* sel_e = (int*)wp; wp += (size_t)TT * 2 * 4;
  int* sel_slot = (int*)wp; wp += (size_t)TT * 2 * 4;
  float* sel_w = (float*)wp; wp += (size_t)TT * 2 * 4;
  unsigned short* hb = (unsigned short*)wp; wp += (size_t)TT * DD * 2;
  unsigned short* gated = (unsigned short*)wp; wp += (size_t)TT * 2 * FF * 2;
  unsigned short* eout = (unsigned short*)wp; wp += (size_t)TT * 2 * DD * 2;
  if ((size_t)(wp - (char*)d_ws) > ws_size) return;  // scratch must fit

  hipMemsetAsync(counts, 0, 32, stream);
  router_kernel<<<TT / 4, 256, 0, stream>>>(h, gw, logits, hb, counts, tok_idx, sel_e, sel_slot, sel_w);
  offsets_kernel<<<1, 64, 0, stream>>>(counts, offsets);
  gemm1_d<<<8 * 16 * 32, 512, 0, stream>>>(w1, w3, hb, tok_idx, counts, offsets, gated);
  gemm2_d<<<8 * 16 * 16, 512, 0, stream>>>(w2, gated, counts, offsets, eout);
  gather_kernel<<<TT * DD / 8 / 256, 256, 0, stream>>>(eout, offsets, sel_e, sel_slot, sel_w, out);
}

// Round 10
// 817.359 us; speedup vs baseline: 1.0769x; 1.0769x over previous
//
#include <hip/hip_runtime.h>
#include <hip/hip_bf16.h>
#include <stdint.h>

#define NE 8
#define DD 2048
#define FF 4096
#define TT 4096      // tokens = 2*2048
#define NCB 49152    // one-shot convert blocks: 3 * nw / (256*16)

typedef __attribute__((ext_vector_type(8))) short bf16x8;
typedef __attribute__((ext_vector_type(4))) float f32x4;

__device__ inline unsigned short f2bf(float f) {
  union { float f; unsigned u; } x; x.f = f;
  unsigned r = x.u + 0x7fffu + ((x.u >> 16) & 1u);
  return (unsigned short)(r >> 16);
}
__device__ inline float bf2f(unsigned short v) {
  union { unsigned u; float f; } x; x.u = (unsigned)v << 16; return x.f;
}

// one-shot 16-element convert: 4 independent loads first (ILP), then 2 stores
__device__ __forceinline__ void conv16(const float* __restrict__ src,
                                       unsigned short* __restrict__ dst, long i) {
  float4 a0 = *(const float4*)(src + i);
  float4 a1 = *(const float4*)(src + i + 4);
  float4 a2 = *(const float4*)(src + i + 8);
  float4 a3 = *(const float4*)(src + i + 12);
  union { unsigned short h[8]; uint4 v; } o0, o1;
  o0.h[0] = f2bf(a0.x); o0.h[1] = f2bf(a0.y); o0.h[2] = f2bf(a0.z); o0.h[3] = f2bf(a0.w);
  o0.h[4] = f2bf(a1.x); o0.h[5] = f2bf(a1.y); o0.h[6] = f2bf(a1.z); o0.h[7] = f2bf(a1.w);
  o1.h[0] = f2bf(a2.x); o1.h[1] = f2bf(a2.y); o1.h[2] = f2bf(a2.z); o1.h[3] = f2bf(a2.w);
  o1.h[4] = f2bf(a3.x); o1.h[5] = f2bf(a3.y); o1.h[6] = f2bf(a3.z); o1.h[7] = f2bf(a3.w);
  *(uint4*)(dst + i) = o0.v;
  *(uint4*)(dst + i + 8) = o1.v;
}

#define GLL16(g, l) __builtin_amdgcn_global_load_lds( \
    (__attribute__((address_space(1))) void*)(void*)(g), \
    (__attribute__((address_space(3))) void*)(l), 16, 0, 0)

// ---------------- router body (one wave = one token) ----------------
__device__ __forceinline__ void router_one(
    int t, int lane, const float* __restrict__ h, const float* __restrict__ gw,
    float* __restrict__ logits, unsigned short* __restrict__ hb,
    int* __restrict__ counts, int* __restrict__ tok_idx,
    int* __restrict__ sel_e, int* __restrict__ sel_slot, float* __restrict__ sel_w) {
  const float4* hr = (const float4*)(h + (size_t)t * DD);
  float4 hv[8];
  float acc[NE];
#pragma unroll
  for (int e = 0; e < NE; e++) acc[e] = 0.f;
#pragma unroll
  for (int j = 0; j < 8; j++) hv[j] = hr[j * 64 + lane];
  ushort4* hbr = (ushort4*)(hb + (size_t)t * DD);
#pragma unroll
  for (int j = 0; j < 8; j++) {
    ushort4 o;
    o.x = f2bf(hv[j].x); o.y = f2bf(hv[j].y); o.z = f2bf(hv[j].z); o.w = f2bf(hv[j].w);
    hbr[j * 64 + lane] = o;
  }
#pragma unroll
  for (int e = 0; e < NE; e++) {
    const float4* g = (const float4*)(gw + (size_t)e * DD);
    float a = 0.f;
#pragma unroll
    for (int j = 0; j < 8; j++) {
      float4 gv = g[j * 64 + lane];
      a += hv[j].x * gv.x + hv[j].y * gv.y + hv[j].z * gv.z + hv[j].w * gv.w;
    }
    acc[e] = a;
  }
#pragma unroll
  for (int e = 0; e < NE; e++) {
    float v = acc[e];
#pragma unroll
    for (int o = 32; o > 0; o >>= 1) v += __shfl_xor(v, o, 64);
    acc[e] = v;
  }
  if (lane == 0) {
#pragma unroll
    for (int e = 0; e < NE; e++) logits[(size_t)t * NE + e] = acc[e];
    int e1 = 0; float m1 = acc[0];
#pragma unroll
    for (int e = 1; e < NE; e++) if (acc[e] > m1) { m1 = acc[e]; e1 = e; }
    int e2 = -1; float m2 = -3.4e38f;
#pragma unroll
    for (int e = 0; e < NE; e++) if (e != e1 && acc[e] > m2) { m2 = acc[e]; e2 = e; }
    float s = expf(m2 - m1);
    float wa = 1.f / (1.f + s);
    float wb = s * wa;
    int s1 = atomicAdd(&counts[e1], 1);
    tok_idx[e1 * TT + s1] = t;
    int s2 = atomicAdd(&counts[e2], 1);
    tok_idx[e2 * TT + s2] = t;
    sel_e[2 * t] = e1; sel_slot[2 * t] = s1; sel_w[2 * t] = wa;
    sel_e[2 * t + 1] = e2; sel_slot[2 * t + 1] = s2; sel_w[2 * t + 1] = wb;
  }
}

// ---------------- prep: one-shot w1/w3/w2 convert + router, one dispatch ----------------
__global__ __launch_bounds__(256) void prep_kernel(
    const float* __restrict__ h, const float* __restrict__ gw,
    float* __restrict__ logits, unsigned short* __restrict__ hb,
    int* __restrict__ counts, int* __restrict__ tok_idx,
    int* __restrict__ sel_e, int* __restrict__ sel_slot, float* __restrict__ sel_w,
    const float* __restrict__ w1, unsigned short* __restrict__ w1b,
    const float* __restrict__ w3, unsigned short* __restrict__ w3b,
    const float* __restrict__ w2, unsigned short* __restrict__ w2b) {
  int b = blockIdx.x;
  if (b < NCB) {
    int t = b >> 14;                 // 16384 blocks per tensor
    long j = ((long)(b & 16383) * 256 + threadIdx.x) * 16;
    const float* src = (t == 0) ? w1 : (t == 1) ? w3 : w2;
    unsigned short* dst = (t == 0) ? w1b : (t == 1) ? w3b : w2b;
    conv16(src, dst, j);
    return;
  }
  int rb = b - NCB;
  router_one(rb * 4 + (threadIdx.x >> 6), threadIdx.x & 63,
             h, gw, logits, hb, counts, tok_idx, sel_e, sel_slot, sel_w);
}

__global__ void offsets_kernel(const int* __restrict__ counts, int* __restrict__ offsets) {
  if (threadIdx.x == 0) {
    int r = 0;
    for (int e = 0; e < NE; e++) { offsets[e] = r; r += counts[e]; }
  }
}

// =========================================================================
// Round-4 proven GEMM structure (m97-class): 2-barrier K-loop, all operands
// bf16 via global_load_lds with pre-swizzled sources, 256 threads, 32KB LDS
// -> 2-3 blocks/CU; inter-block overlap does the latency hiding (m114).
// =========================================================================

// ---- gemm1: gated = silu(X w1^T) * (X w3^T), tile 128(M) x 64(F), BK=64 ----
// grid: 16384 = x(8) * m(32) * q(64); p = x+8q -> n = p&63, e = p>>6
__global__ __launch_bounds__(256) void gemm1_kernel(
    const unsigned short* __restrict__ w1b, const unsigned short* __restrict__ w3b,
    const unsigned short* __restrict__ hb, const int* __restrict__ tok_idx,
    const int* __restrict__ counts, const int* __restrict__ offsets,
    unsigned short* __restrict__ gated) {
  __shared__ __align__(16) char lds[32768];
  char* Ab = lds;              // 128 rows x 128B (bf16)
  char* B1 = lds + 16384;      // 64 rows x 128B
  char* B3 = lds + 24576;      // 64 rows x 128B

  int bid = blockIdx.x;
  int x = bid & 7;
  int rest = bid >> 3;
  int m = rest & 31;
  int q = rest >> 5;
  int p = x + 8 * q;
  int n = p & 63;
  int e = p >> 6;
  int cnt = counts[e];
  int row0 = m * 128;
  if (row0 >= cnt) return;
  int offe = offsets[e];
  int tid = threadIdx.x;

  long asrc[4];
#pragma unroll
  for (int i = 0; i < 4; i++) {
    int r = i * 32 + (tid >> 3);
    int rr = row0 + r; if (rr >= cnt) rr = cnt - 1;
    int tok = tok_idx[e * TT + rr];
    asrc[i] = (long)tok * DD + (((tid & 7) ^ (r & 7)) * 8);
  }
  int fbase = n * 64;
  long ebase = (long)e * FF * DD;
  long bsrc[2];
#pragma unroll
  for (int i = 0; i < 2; i++) {
    int r = i * 32 + (tid >> 3);
    bsrc[i] = ebase + (long)(fbase + r) * DD + (((tid & 7) ^ (r & 7)) * 8);
  }

  f32x4 acc1[4][2], acc3[4][2];
#pragma unroll
  for (int i = 0; i < 4; i++)
#pragma unroll
    for (int j = 0; j < 2; j++) { acc1[i][j] = (f32x4){0,0,0,0}; acc3[i][j] = (f32x4){0,0,0,0}; }

  int wv = tid >> 6;
  int lane = tid & 63;
  int wr = (wv >> 1) * 64;
  int wc = (wv & 1) * 32;
  int lrow = lane & 15;
  int lk4 = lane >> 4;

  for (int k0 = 0; k0 < DD; k0 += 64) {
    if (k0) __syncthreads();
#pragma unroll
    for (int i = 0; i < 4; i++)
      GLL16(hb + asrc[i] + k0, Ab + i * 4096 + tid * 16);
#pragma unroll
    for (int i = 0; i < 2; i++) {
      GLL16(w1b + bsrc[i] + k0, B1 + i * 4096 + tid * 16);
      GLL16(w3b + bsrc[i] + k0, B3 + i * 4096 + tid * 16);
    }
    __syncthreads();
#pragma unroll
    for (int kk = 0; kk < 2; kk++) {
      int kseg = kk * 4 + lk4;
      bf16x8 af[4], b1f[2], b3f[2];
#pragma unroll
      for (int i = 0; i < 4; i++) {
        int row = wr + i * 16 + lrow;
        af[i] = *(const bf16x8*)(Ab + row * 128 + ((kseg ^ (row & 7)) * 16));
      }
#pragma unroll
      for (int j = 0; j < 2; j++) {
        int row = wc + j * 16 + lrow;
        int off = row * 128 + ((kseg ^ (row & 7)) * 16);
        b1f[j] = *(const bf16x8*)(B1 + off);
        b3f[j] = *(const bf16x8*)(B3 + off);
      }
#pragma unroll
      for (int i = 0; i < 4; i++)
#pragma unroll
        for (int j = 0; j < 2; j++) {
          acc1[i][j] = __builtin_amdgcn_mfma_f32_16x16x32_bf16(af[i], b1f[j], acc1[i][j], 0, 0, 0);
          acc3[i][j] = __builtin_amdgcn_mfma_f32_16x16x32_bf16(af[i], b3f[j], acc3[i][j], 0, 0, 0);
        }
    }
  }
  // epilogue: silu(c1)*c3 -> bf16
  int crow0 = wr + (lane >> 4) * 4;
  int ccol0 = wc + (lane & 15);
#pragma unroll
  for (int i = 0; i < 4; i++)
#pragma unroll
    for (int j = 0; j < 2; j++)
#pragma unroll
      for (int r = 0; r < 4; r++) {
        int trow = crow0 + i * 16 + r;
        if (row0 + trow < cnt) {
          float g = acc1[i][j][r];
          float sg = g / (1.f + __expf(-g));
          float val = sg * acc3[i][j][r];
          gated[(size_t)(offe + row0 + trow) * FF + (fbase + ccol0 + j * 16)] = f2bf(val);
        }
      }
}

// ---- gemm2: eout(bf16) = gated w2^T, tile 128(M) x 128(D), BK=64, K=FF ----
// grid: 4096 = x(8) * m(32) * q(16); p = x+8q -> n = p&15, e = p>>4
__global__ __launch_bounds__(256) void gemm2_kernel(
    const unsigned short* __restrict__ w2b, const unsigned short* __restrict__ gated,
    const int* __restrict__ counts, const int* __restrict__ offsets,
    unsigned short* __restrict__ eout) {
  __shared__ __align__(16) char lds[32768];
  char* Ab = lds;              // 128 rows x 128B (bf16)
  char* Bb = lds + 16384;      // 128 rows x 128B

  int bid = blockIdx.x;
  int x = bid & 7;
  int rest = bid >> 3;
  int m = rest & 31;
  int q = rest >> 5;
  int p = x + 8 * q;
  int n = p & 15;
  int e = p >> 4;
  int cnt = counts[e];
  int row0 = m * 128;
  if (row0 >= cnt) return;
  int offe = offsets[e];
  int tid = threadIdx.x;

  long asrc[4];
#pragma unroll
  for (int i = 0; i < 4; i++) {
    int r = i * 32 + (tid >> 3);
    int rr = row0 + r; if (rr >= cnt) rr = cnt - 1;
    asrc[i] = (long)(offe + rr) * FF + (((tid & 7) ^ (r & 7)) * 8);
  }
  int dbase = n * 128;
  long ebase = (long)e * DD * FF;
  long bsrc[4];
#pragma unroll
  for (int i = 0; i < 4; i++) {
    int r = i * 32 + (tid >> 3);
    bsrc[i] = ebase + (long)(dbase + r) * FF + (((tid & 7) ^ (r & 7)) * 8);
  }

  f32x4 acc[4][4];
#pragma unroll
  for (int i = 0; i < 4; i++)
#pragma unroll
    for (int j = 0; j < 4; j++) acc[i][j] = (f32x4){0,0,0,0};

  int wv = tid >> 6;
  int lane = tid & 63;
  int wr = (wv >> 1) * 64;
  int wc = (wv & 1) * 64;
  int lrow = lane & 15;
  int lk4 = lane >> 4;

  for (int k0 = 0; k0 < FF; k0 += 64) {
    if (k0) __syncthreads();
#pragma unroll
    for (int i = 0; i < 4; i++)
      GLL16(gated + asrc[i] + k0, Ab + i * 4096 + tid * 16);
#pragma unroll
    for (int i = 0; i < 4; i++)
      GLL16(w2b + bsrc[i] + k0, Bb + i * 4096 + tid * 16);
    __syncthreads();
#pragma unroll
    for (int kk = 0; kk < 2; kk++) {
      int kseg = kk * 4 + lk4;
      bf16x8 af[4], bf[4];
#pragma unroll
      for (int i = 0; i < 4; i++) {
        int row = wr + i * 16 + lrow;
        af[i] = *(const bf16x8*)(Ab + row * 128 + ((kseg ^ (row & 7)) * 16));
      }
#pragma unroll
      for (int j = 0; j < 4; j++) {
        int row = wc + j * 16 + lrow;
        bf[j] = *(const bf16x8*)(Bb + row * 128 + ((kseg ^ (row & 7)) * 16));
      }
#pragma unroll
      for (int i = 0; i < 4; i++)
#pragma unroll
        for (int j = 0; j < 4; j++)
          acc[i][j] = __builtin_amdgcn_mfma_f32_16x16x32_bf16(af[i], bf[j], acc[i][j], 0, 0, 0);
    }
  }
  int crow0 = wr + (lane >> 4) * 4;
  int ccol0 = wc + (lane & 15);
#pragma unroll
  for (int i = 0; i < 4; i++)
#pragma unroll
    for (int j = 0; j < 4; j++)
#pragma unroll
      for (int r = 0; r < 4; r++) {
        int trow = crow0 + i * 16 + r;
        if (row0 + trow < cnt)
          eout[(size_t)(offe + row0 + trow) * DD + (dbase + ccol0 + j * 16)] = f2bf(acc[i][j][r]);
      }
}

// ---------------- gather: final = sum_k w_k * eout[slot_k] (bf16 eout) ----------------
__global__ void gather_kernel(const unsigned short* __restrict__ eout, const int* __restrict__ offsets,
                              const int* __restrict__ sel_e, const int* __restrict__ sel_slot,
                              const float* __restrict__ sel_w, float* __restrict__ out) {
  int idx = blockIdx.x * 256 + threadIdx.x;
  int t = idx >> 8;            // 256 chunks of 8 per row
  int c = (idx & 255) * 8;
  int ea = sel_e[2 * t], eb = sel_e[2 * t + 1];
  long sa = (long)(offsets[ea] + sel_slot[2 * t]) * DD + c;
  long sb = (long)(offsets[eb] + sel_slot[2 * t + 1]) * DD + c;
  float wa = sel_w[2 * t], wb = sel_w[2 * t + 1];
  union { uint4 v; unsigned short h[8]; } va, vb;
  va.v = *(const uint4*)(eout + sa);
  vb.v = *(const uint4*)(eout + sb);
  float4 o0, o1;
  o0.x = wa * bf2f(va.h[0]) + wb * bf2f(vb.h[0]);
  o0.y = wa * bf2f(va.h[1]) + wb * bf2f(vb.h[1]);
  o0.z = wa * bf2f(va.h[2]) + wb * bf2f(vb.h[2]);
  o0.w = wa * bf2f(va.h[3]) + wb * bf2f(vb.h[3]);
  o1.x = wa * bf2f(va.h[4]) + wb * bf2f(vb.h[4]);
  o1.y = wa * bf2f(va.h[5]) + wb * bf2f(vb.h[5]);
  o1.z = wa * bf2f(va.h[6]) + wb * bf2f(vb.h[6]);
  o1.w = wa * bf2f(va.h[7]) + wb * bf2f(vb.h[7]);
  float* op = out + (size_t)t * DD + c;
  *(float4*)op = o0;
  *(float4*)(op + 4) = o1;
}

extern "C" void kernel_launch(void* const* d_in, const int* in_sizes, int n_in,
                              void* d_out, int out_size, void* d_ws, size_t ws_size,
                              hipStream_t stream) {
  const float* h  = (const float*)d_in[0];
  const float* gw = (const float*)d_in[1];
  const float* w1 = (const float*)d_in[2];
  const float* w2 = (const float*)d_in[3];
  const float* w3 = (const float*)d_in[4];
  float* out = (float*)d_out;
  float* logits = out + (size_t)TT * DD;

  char* wp = (char*)d_ws;
  int* counts = (int*)wp; wp += 256;
  int* offsets = (int*)wp; wp += 256;
  int* tok_idx = (int*)wp; wp += (size_t)NE * TT * 4;
  int* sel_e = (int*)wp; wp += (size_t)TT * 2 * 4;
  int* sel_slot = (int*)wp; wp += (size_t)TT * 2 * 4;
  float* sel_w = (float*)wp; wp += (size_t)TT * 2 * 4;
  unsigned short* hb = (unsigned short*)wp; wp += (size_t)TT * DD * 2;
  unsigned short* gated = (unsigned short*)wp; wp += (size_t)TT * 2 * FF * 2;
  unsigned short* eout = (unsigned short*)wp; wp += (size_t)TT * 2 * DD * 2;
  long nw = (long)NE * FF * DD;
  unsigned short* w1b = (unsigned short*)wp; wp += (size_t)nw * 2;
  unsigned short* w3b = (unsigned short*)wp; wp += (size_t)nw * 2;
  unsigned short* w2b = (unsigned short*)wp; wp += (size_t)nw * 2;
  if ((size_t)(wp - (char*)d_ws) > ws_size) return;  // scratch must fit (verified fits, rounds 3-8)

  hipMemsetAsync(counts, 0, 32, stream);
  prep_kernel<<<NCB + TT / 4, 256, 0, stream>>>(
      h, gw, logits, hb, counts, tok_idx, sel_e, sel_slot, sel_w,
      w1, w1b, w3, w3b, w2, w2b);
  offsets_kernel<<<1, 64, 0, stream>>>(counts, offsets);
  gemm1_kernel<<<8 * 32 * 64, 256, 0, stream>>>(w1b, w3b, hb, tok_idx, counts, offsets, gated);
  gemm2_kernel<<<8 * 32 * 16, 256, 0, stream>>>(w2b, gated, counts, offsets, eout);
  gather_kernel<<<TT * DD / 8 / 256, 256, 0, stream>>>(eout, offsets, sel_e, sel_slot, sel_w, out);
}